// Round 13
// baseline (90.414 us; speedup 1.0000x reference)
//
#include <hip/hip_runtime.h>
#include <math.h>
#include <float.h>
#include <limits.h>

#define NBATCH 4
#define NPROP  4096
#define NCLS   91
#define NFG    90
#define NDET   100
#define CCAP   1024            // per-(image,class) candidate cap (never hit; validated R7-R12)
#define BN     (NBATCH * NPROP)
#define SLOTS  (NFG * NDET)    // 9000 survivor slots per image
#define FCAP   16384           // fallback sort capacity (pow2 >= SLOTS)

static __device__ __forceinline__ float clampf(float x, float lo, float hi) {
    return fminf(fmaxf(x, lo), hi);
}

// Decode + clip one (proposal, class) box. Identical arithmetic everywhere it is
// used -> bitwise-identical results (validated absmax 0.0, R1-R12).
static __device__ __forceinline__ void decode_box(int b, int np, int c,
    const float* __restrict__ props, const float* __restrict__ deltas,
    float W, float H, float& bx1, float& by1, float& bx2, float& by2)
{
    const float* pr = props + ((size_t)b * NPROP + np) * 4;
    const float x1 = pr[0], y1 = pr[1], x2 = pr[2], y2 = pr[3];
    const float w = x2 - x1, h = y2 - y1;
    const float cx = x1 + 0.5f * w, cy = y1 + 0.5f * h;
    const float* d = deltas + (((size_t)b * NPROP + np) * NCLS + c) * 4;
    const float BBC = 4.135166556742356f;   // log(1000/16)
    const float dx = d[0] / 10.0f;
    const float dy = d[1] / 10.0f;
    const float dw = fminf(d[2] / 5.0f, BBC);
    const float dh = fminf(d[3] / 5.0f, BBC);
    const float pcx = dx * w + cx;
    const float pcy = dy * h + cy;
    const float pw = expf(dw) * w;
    const float ph = expf(dh) * h;
    bx1 = clampf(pcx - 0.5f * pw, 0.0f, W);
    by1 = clampf(pcy - 0.5f * ph, 0.0f, H);
    bx2 = clampf(pcx + 0.5f * pw, 0.0f, W);
    by2 = clampf(pcy + 0.5f * ph, 0.0f, H);
}

// Block-wide exclusive scan over 1024 threads (wave shfl scan + wave totals).
static __device__ __forceinline__ int block_excl_scan(int v, int t, int* wtot)
{
    const int lane = t & 63, wid = t >> 6;
    int inc = v;
    #pragma unroll
    for (int s = 1; s < 64; s <<= 1) {
        const int u = __shfl_up(inc, s);
        if (lane >= s) inc += u;
    }
    if (lane == 63) wtot[wid] = inc;
    __syncthreads();
    int base = 0;
    for (int w2 = 0; w2 < wid; ++w2) base += wtot[w2];
    __syncthreads();                 // protect wtot for the next call
    return base + inc - v;
}

// Kernel 1: per-proposal softmax stats + 91-bit FINAL candidate mask.
// UNCHANGED from validated R9-R12.
__global__ __launch_bounds__(256) void stats_mask_kernel(
    const float* __restrict__ logits, const float* __restrict__ props,
    const float* __restrict__ deltas, const int* __restrict__ imgsh,
    float2* __restrict__ stats, unsigned* __restrict__ mask)
{
    const int wavei = threadIdx.x >> 6;
    const int lane  = threadIdx.x & 63;
    const int p = blockIdx.x * 4 + wavei;          // 0 .. B*N-1
    const int b = p >> 12;
    const int np = p & (NPROP - 1);
    const float* lrow = logits + (size_t)p * NCLS;

    const float a  = lrow[lane];
    const float a2 = (lane + 64 < NCLS) ? lrow[lane + 64] : -INFINITY;

    float m = fmaxf(a, a2);                        // level s=64
    #pragma unroll
    for (int s = 32; s > 0; s >>= 1) m = fmaxf(m, __shfl_down(m, s));
    m = __shfl(m, 0);

    const float e0 = expf(a - m);
    const float e1 = (lane + 64 < NCLS) ? expf(a2 - m) : 0.0f;
    float sum = e0 + e1;                           // level s=64
    #pragma unroll
    for (int s = 32; s > 0; s >>= 1) sum += __shfl_down(sum, s);
    sum = __shfl(sum, 0);

    const float W = (float)imgsh[b * 2 + 1];
    const float H = (float)imgsh[b * 2 + 0];

    bool pass0 = ((e0 / sum) > 0.05f) && (lane >= 1);     // class = lane (skip bg 0)
    if (pass0) {
        float bx1, by1, bx2, by2;
        decode_box(b, np, lane, props, deltas, W, H, bx1, by1, bx2, by2);
        pass0 = ((bx2 - bx1) >= 0.01f) && ((by2 - by1) >= 0.01f);
    }
    bool pass1 = ((e1 / sum) > 0.05f);                    // class = lane+64 (<= 90)
    if (pass1) {
        float bx1, by1, bx2, by2;
        decode_box(b, np, lane + 64, props, deltas, W, H, bx1, by1, bx2, by2);
        pass1 = ((bx2 - bx1) >= 0.01f) && ((by2 - by1) >= 0.01f);
    }

    const unsigned long long b0 = __ballot(pass0);        // classes 0..63
    const unsigned long long b1 = __ballot(pass1);        // classes 64..90

    if (lane == 0) {
        stats[p] = make_float2(m, sum);
        mask[p]          = (unsigned)b0;           // plane 0: classes  0..31
        mask[BN + p]     = (unsigned)(b0 >> 32);   // plane 1: classes 32..63
        mask[2 * BN + p] = (unsigned)b1;           // plane 2: classes 64..90
    }
}

// Kernel 2a: one block (256 threads) per (image, class). Gather (two-pass
// deterministic compaction) + bitonic sort descending -> sorted keys to global.
// Logic identical to R12's class_nms through the sort; no decode, no sweep.
__global__ __launch_bounds__(256) void class_sort_kernel(
    const float* __restrict__ logits, const float2* __restrict__ stats,
    const unsigned* __restrict__ mask,
    int* __restrict__ gN, unsigned long long* __restrict__ gKeys)
{
    const int blk  = blockIdx.x;                   // 0..359
    const int b    = blk / NFG;
    const int cm1  = blk % NFG;                    // class - 1
    const int c    = cm1 + 1;
    const int t    = threadIdx.x;
    const int lane = t & 63;
    const int wid  = t >> 6;

    __shared__ unsigned long long sk[CCAP];        // 8 KB, sorted desc, 0 = pad
    __shared__ int wtot[4];

    const unsigned* mp = mask + (size_t)(c >> 5) * BN + b * NPROP;
    const unsigned bit = 1u << (c & 31);

    // ---- pass 1: count final-mask hits (dense coalesced) ----
    int cnt = 0;
    #pragma unroll 4
    for (int np = t; np < NPROP; np += 256) cnt += (mp[np] & bit) ? 1 : 0;

    // ---- exclusive scan over 256 threads ----
    int v = cnt;
    #pragma unroll
    for (int s = 1; s < 64; s <<= 1) {
        const int u = __shfl_up(v, s);
        if (lane >= s) v += u;
    }
    if (lane == 63) wtot[wid] = v;
    __syncthreads();
    int base = 0;
    for (int w2 = 0; w2 < wid; ++w2) base += wtot[w2];
    int pos = base + v - cnt;                      // this thread's exclusive offset
    const int ntot = wtot[0] + wtot[1] + wtot[2] + wtot[3];
    const int n = min(ntot, CCAP);
    if (t == 0) gN[blk] = n;
    if (n == 0) return;

    // ---- pass 2: keys at deterministic positions ----
    for (int np = t; np < NPROP; np += 256) {
        if (!(mp[np] & bit)) continue;
        const int p = b * NPROP + np;
        const float lg = logits[(size_t)p * NCLS + c];
        const float2 st = stats[p];
        const float score = expf(lg - st.x) / st.y;   // bitwise = kernel-1 value
        const unsigned flat = (unsigned)(np * NFG + cm1);
        const unsigned long long key =
            ((unsigned long long)__float_as_uint(score) << 32) | (unsigned)(~flat);
        if (pos < CCAP) sk[pos] = key;
        ++pos;
    }
    __syncthreads();

    // ---- bitonic sort descending on [0, P) ----
    int P = 1; while (P < n) P <<= 1;              // pow2 pad, <= 1024
    for (int i = n + t; i < P; i += 256) sk[i] = 0ULL;

    for (unsigned kk = 2; kk <= (unsigned)P; kk <<= 1) {
        for (unsigned jj = kk >> 1; jj > 0; jj >>= 1) {
            __syncthreads();
            for (unsigned i = t; i < (unsigned)P; i += 256) {
                const unsigned ixj = i ^ jj;
                if (ixj > i) {
                    const unsigned long long x = sk[i], y = sk[ixj];
                    const bool up = ((i & kk) == 0);       // descending when up
                    if (up ? (x < y) : (x > y)) { sk[i] = y; sk[ixj] = x; }
                }
            }
        }
    }
    __syncthreads();

    // ---- write sorted keys (coalesced) ----
    for (int i = t; i < n; i += 256) gKeys[(size_t)blk * CCAP + i] = sk[i];
}

// Kernel 2b: one block (64 threads = 1 wave) per (image, class). Stage sorted
// keys + decode boxes into LDS, then the R12-validated register-survivor
// greedy sweep (prefetched, branchless). One-wave blocks -> all 360 resident.
__global__ __launch_bounds__(64) void class_sweep_kernel(
    const int* __restrict__ gN, const unsigned long long* __restrict__ gKeys,
    const float* __restrict__ props, const float* __restrict__ deltas,
    const int* __restrict__ imgsh, unsigned long long* __restrict__ svKeys)
{
    const int blk  = blockIdx.x;                   // 0..359
    const int b    = blk / NFG;
    const int cm1  = blk % NFG;                    // class - 1
    const int c    = cm1 + 1;
    const int lane = threadIdx.x;                  // 0..63

    __shared__ unsigned long long sk[CCAP];        // 8 KB
    __shared__ float4 sbox[CCAP];                  // 16 KB

    const int n = gN[blk];
    if (n == 0) {
        for (int i = lane; i < NDET; i += 64) svKeys[(size_t)blk * NDET + i] = 0ULL;
        return;
    }

    const float W = (float)imgsh[b * 2 + 1];
    const float H = (float)imgsh[b * 2 + 0];

    // stage keys + decode boxes (identical decode arithmetic)
    for (int i = lane; i < n; i += 64) {
        const unsigned long long key = gKeys[(size_t)blk * CCAP + i];
        sk[i] = key;
        const unsigned flat = ~(unsigned)key;
        const int np = flat / NFG;                 // flat % NFG == cm1 by construction
        float bx1, by1, bx2, by2;
        decode_box(b, np, c, props, deltas, W, H, bx1, by1, bx2, by2);
        sbox[i] = make_float4(bx1, by1, bx2, by2);
    }
    __syncthreads();

    // R12-validated sweep: survivors in registers, prefetched, branchless
    float4 own0 = make_float4(0.f, 0.f, 0.f, 0.f);
    float4 own1 = make_float4(0.f, 0.f, 0.f, 0.f);
    int ns = 0;
    unsigned long long kcur = sk[0];
    float4 bcur = sbox[0];
    for (int i = 0; i < n && ns < NDET; ++i) {
        const unsigned long long key = kcur;
        const float4 Q = bcur;
        const int j = i + 1;
        if (j < n) { kcur = sk[j]; bcur = sbox[j]; }       // prefetch next (hides LDS lat)
        const float aq = (Q.z - Q.x) * (Q.w - Q.y);
        const float iw0 = fmaxf(fminf(own0.z, Q.z) - fmaxf(own0.x, Q.x), 0.0f);
        const float ih0 = fmaxf(fminf(own0.w, Q.w) - fmaxf(own0.y, Q.y), 0.0f);
        const float in0 = iw0 * ih0;
        const float as0 = (own0.z - own0.x) * (own0.w - own0.y);
        const float iw1 = fmaxf(fminf(own1.z, Q.z) - fmaxf(own1.x, Q.x), 0.0f);
        const float ih1 = fmaxf(fminf(own1.w, Q.w) - fmaxf(own1.y, Q.y), 0.0f);
        const float in1 = iw1 * ih1;
        const float as1 = (own1.z - own1.x) * (own1.w - own1.y);
        const bool sup = (in0 / (as0 + aq - in0) > 0.5f) ||
                         (in1 / (as1 + aq - in1) > 0.5f);
        if (!__any(sup)) {
            if (lane == (ns & 63)) { if (ns < 64) own0 = Q; else own1 = Q; }
            if (lane == 0) svKeys[(size_t)blk * NDET + ns] = key;
            ++ns;
        }
    }
    // zero-fill unused slots (deterministic)
    for (int i = ns + lane; i < NDET; i += 64) svKeys[(size_t)blk * NDET + i] = 0ULL;
}

// Kernel 3: radix-select top-100. UNCHANGED from validated R12.
__global__ __launch_bounds__(1024) void select_kernel(
    const unsigned long long* __restrict__ svKeys,
    const float* __restrict__ props, const float* __restrict__ deltas,
    const int* __restrict__ imgsh, float* __restrict__ out)
{
    const int b = blockIdx.x;
    const int t = threadIdx.x;
    __shared__ unsigned long long F[FCAP];         // 128 KB (sort buffer)
    __shared__ int hist[4096];                     // 16 KB
    __shared__ int wtot[16];
    __shared__ int s_T, s_above, s_total;

    if (t == 0) { s_T = -1; s_above = 0; s_total = 0; }
    #pragma unroll
    for (int j = 0; j < 4; ++j) hist[t + j * 1024] = 0;

    const unsigned long long* src = svKeys + (size_t)b * SLOTS;
    unsigned long long keys[9];
    #pragma unroll
    for (int j = 0; j < 9; ++j) {
        const int s = t + j * 1024;
        keys[j] = (s < SLOTS) ? src[s] : 0ULL;
    }
    __syncthreads();

    #pragma unroll
    for (int j = 0; j < 9; ++j) {
        if (keys[j] != 0ULL) atomicAdd(&hist[(unsigned)(keys[j] >> 52)], 1);
    }
    __syncthreads();

    {
        const int gbase = (1023 - t) * 4;
        const int s0 = hist[gbase] + hist[gbase + 1] + hist[gbase + 2] + hist[gbase + 3];
        const int pre = block_excl_scan(s0, t, wtot);   // counts in all higher buckets
        int acc = pre;
        for (int d = gbase + 3; d >= gbase; --d) {
            const int h = hist[d];
            if (acc < NDET && acc + h >= NDET) { s_T = d; s_above = acc; }  // unique
            acc += h;
        }
        if (t == 1023) s_total = acc;              // lowest group finishes the total
    }
    __syncthreads();

    const int T = s_T;
    const int total = s_total;
    const int n2 = (T < 0) ? total : (s_above + hist[T]);
    const bool fast = (n2 <= 2048);

    int mycnt = 0;
    #pragma unroll
    for (int j = 0; j < 9; ++j) {
        const unsigned long long k = keys[j];
        const bool m = (k != 0ULL) && (fast ? (T < 0 || (int)(k >> 52) >= T) : true);
        mycnt += m ? 1 : 0;
    }
    int off = block_excl_scan(mycnt, t, wtot);
    #pragma unroll
    for (int j = 0; j < 9; ++j) {
        const unsigned long long k = keys[j];
        const bool m = (k != 0ULL) && (fast ? (T < 0 || (int)(k >> 52) >= T) : true);
        if (m) F[off++] = k;
    }
    const int nsort = fast ? n2 : total;

    int P = 128; while (P < nsort) P <<= 1;        // pow2 pad, >= 128, <= FCAP
    for (int i = nsort + t; i < P; i += 1024) F[i] = 0ULL;

    for (unsigned kk = 2; kk <= (unsigned)P; kk <<= 1) {
        for (unsigned jj = kk >> 1; jj > 0; jj >>= 1) {
            __syncthreads();
            for (unsigned i = t; i < (unsigned)P; i += 1024) {
                const unsigned ixj = i ^ jj;
                if (ixj > i) {
                    const unsigned long long x = F[i], y = F[ixj];
                    const bool up = ((i & kk) == 0);       // descending when up
                    if (up ? (x < y) : (x > y)) { F[i] = y; F[ixj] = x; }
                }
            }
        }
    }
    __syncthreads();

    float* oB = out + (size_t)b * NDET * 4;
    float* oS = out + (size_t)NBATCH * NDET * 4 + (size_t)b * NDET;
    float* oL = out + (size_t)NBATCH * NDET * 5 + (size_t)b * NDET;
    if (t < NDET) {
        const unsigned long long key = F[t];       // P >= 128 > NDET, zero-padded
        if (key != 0ULL) {
            const unsigned flat = ~(unsigned)key;
            const float score = __uint_as_float((unsigned)(key >> 32));
            const int np = flat / NFG;
            const int c  = (int)(flat - (unsigned)np * NFG) + 1;
            const float W = (float)imgsh[b * 2 + 1];
            const float H = (float)imgsh[b * 2 + 0];
            float bx1, by1, bx2, by2;
            decode_box(b, np, c, props, deltas, W, H, bx1, by1, bx2, by2);
            oB[t * 4 + 0] = bx1; oB[t * 4 + 1] = by1;
            oB[t * 4 + 2] = bx2; oB[t * 4 + 3] = by2;
            oS[t] = score;
            oL[t] = (float)c;
        } else {
            oB[t * 4 + 0] = 0.0f; oB[t * 4 + 1] = 0.0f;
            oB[t * 4 + 2] = 0.0f; oB[t * 4 + 3] = 0.0f;
            oS[t] = 0.0f; oL[t] = -1.0f;
        }
    }
}

extern "C" void kernel_launch(void* const* d_in, const int* in_sizes, int n_in,
                              void* d_out, int out_size, void* d_ws, size_t ws_size,
                              hipStream_t stream)
{
    const float* logits = (const float*)d_in[0];   // [B*N, 91]
    const float* deltas = (const float*)d_in[1];   // [B*N, 364]
    const float* props  = (const float*)d_in[2];   // [B, N, 4]
    const int*   imgsh  = (const int*)d_in[3];     // [B, 2]
    float* out = (float*)d_out;

    char* w = (char*)d_ws;
    float2* stats = (float2*)w;            w += (size_t)BN * sizeof(float2);       // 128 KB
    unsigned* mask = (unsigned*)w;         w += (size_t)3 * BN * sizeof(unsigned); // 192 KB
    unsigned long long* svKeys = (unsigned long long*)w;
    w += (size_t)NBATCH * SLOTS * sizeof(unsigned long long);                      // 288 KB
    int* gN = (int*)w;                     w += 4096;                              // 360 counts
    unsigned long long* gKeys = (unsigned long long*)w;
    w += (size_t)NBATCH * NFG * CCAP * sizeof(unsigned long long);                 // ~2.95 MB

    stats_mask_kernel<<<BN / 4, 256, 0, stream>>>(logits, props, deltas, imgsh, stats, mask);
    class_sort_kernel<<<NBATCH * NFG, 256, 0, stream>>>(logits, stats, mask, gN, gKeys);
    class_sweep_kernel<<<NBATCH * NFG, 64, 0, stream>>>(gN, gKeys, props, deltas, imgsh, svKeys);
    select_kernel<<<NBATCH, 1024, 0, stream>>>(svKeys, props, deltas, imgsh, out);
}

// Round 14
// 80.092 us; speedup vs baseline: 1.1289x; 1.1289x over previous
//
#include <hip/hip_runtime.h>
#include <math.h>
#include <float.h>
#include <limits.h>

#define NBATCH 4
#define NPROP  4096
#define NCLS   91
#define NFG    90
#define NDET   100
#define CCAP   1024            // per-(image,class) candidate cap (never hit; validated R7-R13)
#define BN     (NBATCH * NPROP)
#define SLOTS  (NFG * NDET)    // 9000 survivor slots per image
#define FCAP   16384           // fallback sort capacity (pow2 >= SLOTS)
#define CHUNK  128             // NMS matrix-walk chunk size

static __device__ __forceinline__ float clampf(float x, float lo, float hi) {
    return fminf(fmaxf(x, lo), hi);
}

// Decode + clip one (proposal, class) box. Identical arithmetic everywhere it is
// used -> bitwise-identical results (validated absmax 0.0, R1-R13).
static __device__ __forceinline__ void decode_box(int b, int np, int c,
    const float* __restrict__ props, const float* __restrict__ deltas,
    float W, float H, float& bx1, float& by1, float& bx2, float& by2)
{
    const float* pr = props + ((size_t)b * NPROP + np) * 4;
    const float x1 = pr[0], y1 = pr[1], x2 = pr[2], y2 = pr[3];
    const float w = x2 - x1, h = y2 - y1;
    const float cx = x1 + 0.5f * w, cy = y1 + 0.5f * h;
    const float* d = deltas + (((size_t)b * NPROP + np) * NCLS + c) * 4;
    const float BBC = 4.135166556742356f;   // log(1000/16)
    const float dx = d[0] / 10.0f;
    const float dy = d[1] / 10.0f;
    const float dw = fminf(d[2] / 5.0f, BBC);
    const float dh = fminf(d[3] / 5.0f, BBC);
    const float pcx = dx * w + cx;
    const float pcy = dy * h + cy;
    const float pw = expf(dw) * w;
    const float ph = expf(dh) * h;
    bx1 = clampf(pcx - 0.5f * pw, 0.0f, W);
    by1 = clampf(pcy - 0.5f * ph, 0.0f, H);
    bx2 = clampf(pcx + 0.5f * pw, 0.0f, W);
    by2 = clampf(pcy + 0.5f * ph, 0.0f, H);
}

// IoU > 0.5 predicate, identical float expression to all validated rounds.
static __device__ __forceinline__ bool iou_gt(const float4 S, const float4 Q, float aq)
{
    const float iw = fmaxf(fminf(S.z, Q.z) - fmaxf(S.x, Q.x), 0.0f);
    const float ih = fmaxf(fminf(S.w, Q.w) - fmaxf(S.y, Q.y), 0.0f);
    const float inter = iw * ih;
    const float as = (S.z - S.x) * (S.w - S.y);
    return inter / (as + aq - inter) > 0.5f;
}

// Block-wide exclusive scan over 1024 threads (wave shfl scan + wave totals).
static __device__ __forceinline__ int block_excl_scan(int v, int t, int* wtot)
{
    const int lane = t & 63, wid = t >> 6;
    int inc = v;
    #pragma unroll
    for (int s = 1; s < 64; s <<= 1) {
        const int u = __shfl_up(inc, s);
        if (lane >= s) inc += u;
    }
    if (lane == 63) wtot[wid] = inc;
    __syncthreads();
    int base = 0;
    for (int w2 = 0; w2 < wid; ++w2) base += wtot[w2];
    __syncthreads();                 // protect wtot for the next call
    return base + inc - v;
}

// Kernel 1: per-proposal softmax stats + 91-bit FINAL candidate mask.
// UNCHANGED from validated R9-R13.
__global__ __launch_bounds__(256) void stats_mask_kernel(
    const float* __restrict__ logits, const float* __restrict__ props,
    const float* __restrict__ deltas, const int* __restrict__ imgsh,
    float2* __restrict__ stats, unsigned* __restrict__ mask)
{
    const int wavei = threadIdx.x >> 6;
    const int lane  = threadIdx.x & 63;
    const int p = blockIdx.x * 4 + wavei;          // 0 .. B*N-1
    const int b = p >> 12;
    const int np = p & (NPROP - 1);
    const float* lrow = logits + (size_t)p * NCLS;

    const float a  = lrow[lane];
    const float a2 = (lane + 64 < NCLS) ? lrow[lane + 64] : -INFINITY;

    float m = fmaxf(a, a2);                        // level s=64
    #pragma unroll
    for (int s = 32; s > 0; s >>= 1) m = fmaxf(m, __shfl_down(m, s));
    m = __shfl(m, 0);

    const float e0 = expf(a - m);
    const float e1 = (lane + 64 < NCLS) ? expf(a2 - m) : 0.0f;
    float sum = e0 + e1;                           // level s=64
    #pragma unroll
    for (int s = 32; s > 0; s >>= 1) sum += __shfl_down(sum, s);
    sum = __shfl(sum, 0);

    const float W = (float)imgsh[b * 2 + 1];
    const float H = (float)imgsh[b * 2 + 0];

    bool pass0 = ((e0 / sum) > 0.05f) && (lane >= 1);     // class = lane (skip bg 0)
    if (pass0) {
        float bx1, by1, bx2, by2;
        decode_box(b, np, lane, props, deltas, W, H, bx1, by1, bx2, by2);
        pass0 = ((bx2 - bx1) >= 0.01f) && ((by2 - by1) >= 0.01f);
    }
    bool pass1 = ((e1 / sum) > 0.05f);                    // class = lane+64 (<= 90)
    if (pass1) {
        float bx1, by1, bx2, by2;
        decode_box(b, np, lane + 64, props, deltas, W, H, bx1, by1, bx2, by2);
        pass1 = ((bx2 - bx1) >= 0.01f) && ((by2 - by1) >= 0.01f);
    }

    const unsigned long long b0 = __ballot(pass0);        // classes 0..63
    const unsigned long long b1 = __ballot(pass1);        // classes 64..90

    if (lane == 0) {
        stats[p] = make_float2(m, sum);
        mask[p]          = (unsigned)b0;           // plane 0: classes  0..31
        mask[BN + p]     = (unsigned)(b0 >> 32);   // plane 1: classes 32..63
        mask[2 * BN + p] = (unsigned)b1;           // plane 2: classes 64..90
    }
}

// Kernel 2: one block (256 threads) per (image, class). Gather -> sort ->
// decode (R12-validated), then CHUNKED SUPPRESSION-MATRIX greedy NMS:
// exactly equivalent to the sorted greedy sweep (survivor <=> no earlier
// survivor with IoU>0.5), but the serial walk is bitmask-only (~30 cy/step).
__global__ __launch_bounds__(256) void class_nms_kernel(
    const float* __restrict__ logits, const float2* __restrict__ stats,
    const unsigned* __restrict__ mask,
    const float* __restrict__ props, const float* __restrict__ deltas,
    const int* __restrict__ imgsh, unsigned long long* __restrict__ svKeys)
{
    const int blk  = blockIdx.x;                   // 0..359
    const int b    = blk / NFG;
    const int cm1  = blk % NFG;                    // class - 1
    const int c    = cm1 + 1;
    const int t    = threadIdx.x;
    const int lane = t & 63;
    const int wid  = t >> 6;

    __shared__ unsigned long long sk[CCAP];        // 8 KB, sorted desc, 0 = pad
    __shared__ float4 sbox[CCAP];                  // 16 KB
    __shared__ unsigned long long mrow[CHUNK][2];  // 2 KB in-chunk suppression matrix
    __shared__ float4 sOwn[NDET];                  // 1.6 KB accepted survivor boxes
    __shared__ unsigned long long sPreW[2];
    __shared__ int wtot[4];
    __shared__ int s_ns;

    const float W = (float)imgsh[b * 2 + 1];
    const float H = (float)imgsh[b * 2 + 0];

    const unsigned* mp = mask + (size_t)(c >> 5) * BN + b * NPROP;
    const unsigned bit = 1u << (c & 31);

    // ---- pass 1: count final-mask hits (dense coalesced) ----
    int cnt = 0;
    #pragma unroll 4
    for (int np = t; np < NPROP; np += 256) cnt += (mp[np] & bit) ? 1 : 0;

    // ---- exclusive scan over 256 threads ----
    int v = cnt;
    #pragma unroll
    for (int s = 1; s < 64; s <<= 1) {
        const int u = __shfl_up(v, s);
        if (lane >= s) v += u;
    }
    if (lane == 63) wtot[wid] = v;
    __syncthreads();
    int base = 0;
    for (int w2 = 0; w2 < wid; ++w2) base += wtot[w2];
    int pos = base + v - cnt;                      // this thread's exclusive offset
    const int ntot = wtot[0] + wtot[1] + wtot[2] + wtot[3];
    const int n = min(ntot, CCAP);
    if (n == 0) {
        for (int i = t; i < NDET; i += 256) svKeys[(size_t)blk * NDET + i] = 0ULL;
        return;
    }

    // ---- pass 2: keys at deterministic positions ----
    for (int np = t; np < NPROP; np += 256) {
        if (!(mp[np] & bit)) continue;
        const int p = b * NPROP + np;
        const float lg = logits[(size_t)p * NCLS + c];
        const float2 st = stats[p];
        const float score = expf(lg - st.x) / st.y;   // bitwise = kernel-1 value
        const unsigned flat = (unsigned)(np * NFG + cm1);
        const unsigned long long key =
            ((unsigned long long)__float_as_uint(score) << 32) | (unsigned)(~flat);
        if (pos < CCAP) sk[pos] = key;
        ++pos;
    }
    __syncthreads();

    // ---- bitonic sort descending on [0, P) ----
    int P = 1; while (P < n) P <<= 1;              // pow2 pad, <= 1024
    for (int i = n + t; i < P; i += 256) sk[i] = 0ULL;

    for (unsigned kk = 2; kk <= (unsigned)P; kk <<= 1) {
        for (unsigned jj = kk >> 1; jj > 0; jj >>= 1) {
            __syncthreads();
            for (unsigned i = t; i < (unsigned)P; i += 256) {
                const unsigned ixj = i ^ jj;
                if (ixj > i) {
                    const unsigned long long x = sk[i], y = sk[ixj];
                    const bool up = ((i & kk) == 0);       // descending when up
                    if (up ? (x < y) : (x > y)) { sk[i] = y; sk[ixj] = x; }
                }
            }
        }
    }
    __syncthreads();

    // ---- decode boxes ONCE for sorted candidates ----
    for (int i = t; i < n; i += 256) {
        const unsigned flat = ~(unsigned)sk[i];
        const int np = flat / NFG;                 // flat % NFG == cm1 by construction
        float bx1, by1, bx2, by2;
        decode_box(b, np, c, props, deltas, W, H, bx1, by1, bx2, by2);
        sbox[i] = make_float4(bx1, by1, bx2, by2);
    }
    if (t == 0) s_ns = 0;
    __syncthreads();

    // ---- chunked suppression-matrix greedy NMS ----
    int nsTot = 0;
    for (int cb = 0; cb < n && nsTot < NDET; cb += CHUNK) {
        const int C = min(CHUNK, n - cb);

        // (a) pre-suppression vs accepted survivors (free on chunk 1: nsTot==0)
        bool pre = false;
        if (t < C) {
            const float4 Q = sbox[cb + t];
            const float aq = (Q.z - Q.x) * (Q.w - Q.y);
            for (int l = 0; l < nsTot; ++l) {
                if (iou_gt(sOwn[l], Q, aq)) { pre = true; break; }
            }
        }
        const unsigned long long bal = __ballot(pre);
        if (t == 0)  sPreW[0] = bal;               // chunk idx 0..63
        if (t == 64) sPreW[1] = bal;               // chunk idx 64..127

        // (b) in-chunk suppression matrix: thread t -> row r = t>>1, word w = t&1
        {
            const int r = t >> 1, w = t & 1;
            unsigned long long word = 0ULL;
            if (r < C) {
                const float4 R = sbox[cb + r];     // row box (the earlier/suppressor)
                const int j0 = w * 64;
                const int jend = min(j0 + 64, C);
                for (int j = (j0 > r + 1 ? j0 : r + 1); j < jend; ++j) {
                    const float4 Q = sbox[cb + j];
                    const float aq = (Q.z - Q.x) * (Q.w - Q.y);
                    if (iou_gt(R, Q, aq)) word |= (1ULL << (j - j0));
                }
            }
            mrow[r][w] = word;
        }
        __syncthreads();

        // (c) scalar bitmask walk (thread 0): ~30-40 cy/step, prefetched rows
        if (t == 0) {
            unsigned long long S0 = sPreW[0], S1 = sPreW[1];
            int ns = nsTot;
            unsigned long long r0 = mrow[0][0], r1 = mrow[0][1];
            for (int i = 0; i < C && ns < NDET; ++i) {
                const unsigned long long nr0 = (i + 1 < C) ? mrow[i + 1][0] : 0ULL;
                const unsigned long long nr1 = (i + 1 < C) ? mrow[i + 1][1] : 0ULL;
                const bool dead = (i < 64) ? ((S0 >> i) & 1ULL)
                                           : ((S1 >> (i - 64)) & 1ULL);
                if (!dead) {
                    sOwn[ns] = sbox[cb + i];
                    svKeys[(size_t)blk * NDET + ns] = sk[cb + i];
                    ++ns;
                    S0 |= r0; S1 |= r1;
                }
                r0 = nr0; r1 = nr1;
            }
            s_ns = ns;
        }
        __syncthreads();
        nsTot = s_ns;
    }

    // zero-fill unused survivor slots (deterministic)
    for (int i = nsTot + t; i < NDET; i += 256) svKeys[(size_t)blk * NDET + i] = 0ULL;
}

// Kernel 3: radix-select top-100. UNCHANGED from validated R12/R13.
__global__ __launch_bounds__(1024) void select_kernel(
    const unsigned long long* __restrict__ svKeys,
    const float* __restrict__ props, const float* __restrict__ deltas,
    const int* __restrict__ imgsh, float* __restrict__ out)
{
    const int b = blockIdx.x;
    const int t = threadIdx.x;
    __shared__ unsigned long long F[FCAP];         // 128 KB (sort buffer)
    __shared__ int hist[4096];                     // 16 KB
    __shared__ int wtot[16];
    __shared__ int s_T, s_above, s_total;

    if (t == 0) { s_T = -1; s_above = 0; s_total = 0; }
    #pragma unroll
    for (int j = 0; j < 4; ++j) hist[t + j * 1024] = 0;

    const unsigned long long* src = svKeys + (size_t)b * SLOTS;
    unsigned long long keys[9];
    #pragma unroll
    for (int j = 0; j < 9; ++j) {
        const int s = t + j * 1024;
        keys[j] = (s < SLOTS) ? src[s] : 0ULL;
    }
    __syncthreads();

    #pragma unroll
    for (int j = 0; j < 9; ++j) {
        if (keys[j] != 0ULL) atomicAdd(&hist[(unsigned)(keys[j] >> 52)], 1);
    }
    __syncthreads();

    {
        const int gbase = (1023 - t) * 4;
        const int s0 = hist[gbase] + hist[gbase + 1] + hist[gbase + 2] + hist[gbase + 3];
        const int pre = block_excl_scan(s0, t, wtot);   // counts in all higher buckets
        int acc = pre;
        for (int d = gbase + 3; d >= gbase; --d) {
            const int h = hist[d];
            if (acc < NDET && acc + h >= NDET) { s_T = d; s_above = acc; }  // unique
            acc += h;
        }
        if (t == 1023) s_total = acc;              // lowest group finishes the total
    }
    __syncthreads();

    const int T = s_T;
    const int total = s_total;
    const int n2 = (T < 0) ? total : (s_above + hist[T]);
    const bool fast = (n2 <= 2048);

    int mycnt = 0;
    #pragma unroll
    for (int j = 0; j < 9; ++j) {
        const unsigned long long k = keys[j];
        const bool m = (k != 0ULL) && (fast ? (T < 0 || (int)(k >> 52) >= T) : true);
        mycnt += m ? 1 : 0;
    }
    int off = block_excl_scan(mycnt, t, wtot);
    #pragma unroll
    for (int j = 0; j < 9; ++j) {
        const unsigned long long k = keys[j];
        const bool m = (k != 0ULL) && (fast ? (T < 0 || (int)(k >> 52) >= T) : true);
        if (m) F[off++] = k;
    }
    const int nsort = fast ? n2 : total;

    int P = 128; while (P < nsort) P <<= 1;        // pow2 pad, >= 128, <= FCAP
    for (int i = nsort + t; i < P; i += 1024) F[i] = 0ULL;

    for (unsigned kk = 2; kk <= (unsigned)P; kk <<= 1) {
        for (unsigned jj = kk >> 1; jj > 0; jj >>= 1) {
            __syncthreads();
            for (unsigned i = t; i < (unsigned)P; i += 1024) {
                const unsigned ixj = i ^ jj;
                if (ixj > i) {
                    const unsigned long long x = F[i], y = F[ixj];
                    const bool up = ((i & kk) == 0);       // descending when up
                    if (up ? (x < y) : (x > y)) { F[i] = y; F[ixj] = x; }
                }
            }
        }
    }
    __syncthreads();

    float* oB = out + (size_t)b * NDET * 4;
    float* oS = out + (size_t)NBATCH * NDET * 4 + (size_t)b * NDET;
    float* oL = out + (size_t)NBATCH * NDET * 5 + (size_t)b * NDET;
    if (t < NDET) {
        const unsigned long long key = F[t];       // P >= 128 > NDET, zero-padded
        if (key != 0ULL) {
            const unsigned flat = ~(unsigned)key;
            const float score = __uint_as_float((unsigned)(key >> 32));
            const int np = flat / NFG;
            const int c  = (int)(flat - (unsigned)np * NFG) + 1;
            const float W = (float)imgsh[b * 2 + 1];
            const float H = (float)imgsh[b * 2 + 0];
            float bx1, by1, bx2, by2;
            decode_box(b, np, c, props, deltas, W, H, bx1, by1, bx2, by2);
            oB[t * 4 + 0] = bx1; oB[t * 4 + 1] = by1;
            oB[t * 4 + 2] = bx2; oB[t * 4 + 3] = by2;
            oS[t] = score;
            oL[t] = (float)c;
        } else {
            oB[t * 4 + 0] = 0.0f; oB[t * 4 + 1] = 0.0f;
            oB[t * 4 + 2] = 0.0f; oB[t * 4 + 3] = 0.0f;
            oS[t] = 0.0f; oL[t] = -1.0f;
        }
    }
}

extern "C" void kernel_launch(void* const* d_in, const int* in_sizes, int n_in,
                              void* d_out, int out_size, void* d_ws, size_t ws_size,
                              hipStream_t stream)
{
    const float* logits = (const float*)d_in[0];   // [B*N, 91]
    const float* deltas = (const float*)d_in[1];   // [B*N, 364]
    const float* props  = (const float*)d_in[2];   // [B, N, 4]
    const int*   imgsh  = (const int*)d_in[3];     // [B, 2]
    float* out = (float*)d_out;

    char* w = (char*)d_ws;
    float2* stats = (float2*)w;            w += (size_t)BN * sizeof(float2);       // 128 KB
    unsigned* mask = (unsigned*)w;         w += (size_t)3 * BN * sizeof(unsigned); // 192 KB
    unsigned long long* svKeys = (unsigned long long*)w;
    w += (size_t)NBATCH * SLOTS * sizeof(unsigned long long);                      // 288 KB

    stats_mask_kernel<<<BN / 4, 256, 0, stream>>>(logits, props, deltas, imgsh, stats, mask);
    class_nms_kernel<<<NBATCH * NFG, 256, 0, stream>>>(
        logits, stats, mask, props, deltas, imgsh, svKeys);
    select_kernel<<<NBATCH, 1024, 0, stream>>>(svKeys, props, deltas, imgsh, out);
}